// Round 9
// baseline (599.591 us; speedup 1.0000x reference)
//
#include <hip/hip_runtime.h>
#include <math.h>

// Problem constants (fixed by the reference).
#define NUM_K   512        // codebook entries
#define DIM     64         // embedding dim (== C)
#define NROWS   131072     // 32*64*64 flattened (b,h,w) rows
#define NELEM   8388608    // NROWS*DIM
// d_out layout (float32, concatenated in return order):
// [0] loss ; [1..1+NELEM) quantized NCHW ; [1+NELEM] perplexity ;
// [2+NELEM..) codebook_indices (as float)
#define Q_OFF    1
#define PERP_OFF 8388609
#define IDX_OFF  8388610

// Flag threshold (validated rounds 6-8): rows with approx gap >= THRESH
// provably share the reference argmin; others re-done bitwise in vq_fix.
#define THRESH  1.25e-4f

typedef short  bf16x8 __attribute__((ext_vector_type(8)));
typedef float  f32x4  __attribute__((ext_vector_type(4)));

// ws layout:
//   [0,4)          float loss_sum
//   [16,2064)      uint  counts[512]
//   [4096,6144)    float swsq_g[512]        (frozen bitwise ||w_k||^2)
//   [8192,139264)  ushort wpack[65536]      (B-fragment-packed hi/lo codebook)
//   [139264,270336) float wt[64][512]       (fp32 transposed codebook, bitwise)

__device__ __forceinline__ unsigned short f2bf(float f) {  // RNE f32->bf16
    unsigned u = __float_as_uint(f);
    return (unsigned short)((u + 0x7FFFu + ((u >> 16) & 1u)) >> 16);
}
__device__ __forceinline__ float bf2f(unsigned short h) {
    return __uint_as_float(((unsigned)h) << 16);
}

// Prep: frozen wsq (validated) + B-fragment hi/lo packing (validated) +
// fp32 transposed codebook wt[c][k] = w[k][c] (bitwise copy).
__global__ __launch_bounds__(256) void vq_prep(const float* __restrict__ w,
                                               float* __restrict__ swsq_g,
                                               unsigned short* __restrict__ wpack,
                                               float* __restrict__ wt) {
    const int id = blockIdx.x * 256 + threadIdx.x;   // 0..32767
    if (id < NUM_K) {
        const float* wk = w + id * DIM;
        float r[8];
#pragma unroll
        for (int j = 0; j < 8; ++j) r[j] = __fmul_rn(wk[j], wk[j]);
#pragma unroll
        for (int t = 1; t < 8; ++t)
#pragma unroll
            for (int j = 0; j < 8; ++j)
                r[j] = __fadd_rn(r[j], __fmul_rn(wk[8 * t + j], wk[8 * t + j]));
        swsq_g[id] = __fadd_rn(
            __fadd_rn(__fadd_rn(r[0], r[1]), __fadd_rn(r[2], r[3])),
            __fadd_rn(__fadd_rn(r[4], r[5]), __fadd_rn(r[6], r[7])));
    }
    if (id < 8192) {
        const int kt = id >> 8, f = (id >> 6) & 3, l = id & 63;
        const int step = f >> 1, pass = f & 1;
        const int coln = kt * 16 + (l & 15), quad = l >> 4;
        const float* src = w + (size_t)coln * DIM + step * 32 + quad * 8;
        unsigned short tmp[8];
#pragma unroll
        for (int j = 0; j < 8; ++j) {
            float v = src[j];
            unsigned short hi = f2bf(v);
            tmp[j] = pass ? f2bf(v - bf2f(hi)) : hi;
        }
        *(uint4*)(wpack + (size_t)id * 8) = *(uint4*)tmp;
    }
    wt[id] = w[(id & 511) * DIM + (id >> 9)];   // bitwise transpose
}

// Phase 1: MFMA filter. Rolling k-loop (round-7 structure, proven no-spill)
// upgraded to depth-2 double-buffered B prefetch inside #pragma unroll 1.
// Flagged rows get out_idx = -1 (picked up by vq_fix); no flaglist/atomic.
__global__ __launch_bounds__(256, 3) void vq_phase1(
        const float* __restrict__ x,
        const float* __restrict__ w,
        const float* __restrict__ swsq_g,
        const uint4* __restrict__ wpack,
        float* __restrict__ out_q,
        float* __restrict__ out_idx,
        float* __restrict__ loss_sum,
        unsigned* __restrict__ counts) {
    __shared__ float swsq[NUM_K];          // 2 KB
    __shared__ unsigned hcnt[NUM_K];       // 2 KB
    __shared__ int sidx[128];
    __shared__ float wred[4];

    const int tid  = threadIdx.x;
    const int lane = tid & 63;
    const int wvid = tid >> 6;
    const int quad = lane >> 4;
    const int m    = lane & 15;
    const int n0   = blockIdx.x * 128;
    const int b    = n0 >> 12;
    const int hw0  = n0 & 4095;
    const float* xbase = x + (size_t)b * 262144 + hw0;

    for (int i = tid; i < NUM_K; i += 256) { swsq[i] = swsq_g[i]; hcnt[i] = 0; }

    // A fragments in registers: afr[rt][step][pass], rt=row-tile (16 rows).
    bf16x8 afr[2][2][2];
#pragma unroll
    for (int rt = 0; rt < 2; ++rt) {
        const int row = wvid * 32 + rt * 16 + m;
        const float* xp = xbase + row;
#pragma unroll
        for (int s = 0; s < 2; ++s) {
            union { bf16x8 v; unsigned short u[8]; } hi, lo;
#pragma unroll
            for (int j = 0; j < 8; ++j) {
                float v = xp[(size_t)(s * 32 + quad * 8 + j) * 4096];
                unsigned short h = f2bf(v);
                hi.u[j] = h;
                lo.u[j] = f2bf(v - bf2f(h));
            }
            afr[rt][s][0] = hi.v;
            afr[rt][s][1] = lo.v;
        }
    }
    __syncthreads();   // swsq/hcnt ready

    float min1[2][4], min2[2][4]; int idx[2][4];
#pragma unroll
    for (int rt = 0; rt < 2; ++rt)
#pragma unroll
        for (int r = 0; r < 4; ++r) {
            min1[rt][r] = 3.4e38f; min2[rt][r] = 3.4e38f; idx[rt][r] = 0;
        }

    // Depth-2 double-buffered B prefetch; rolling loop, bounded live ranges.
    uint4 P[2][4];
    {
        const uint4* t0 = wpack;
        const uint4* t1 = wpack + 256;
#pragma unroll
        for (int q = 0; q < 4; ++q) { P[0][q] = t0[q * 64 + lane];
                                      P[1][q] = t1[q * 64 + lane]; }
    }
#pragma unroll 1
    for (int kt = 0; kt < 32; kt += 2) {
#pragma unroll
        for (int h = 0; h < 2; ++h) {
            bf16x8 bh0 = __builtin_bit_cast(bf16x8, P[h][0]);
            bf16x8 bl0 = __builtin_bit_cast(bf16x8, P[h][1]);
            bf16x8 bh1 = __builtin_bit_cast(bf16x8, P[h][2]);
            bf16x8 bl1 = __builtin_bit_cast(bf16x8, P[h][3]);
            const int kg = (kt + h) * 16 + m;
            const float wsqv = swsq[kg];
            if (kt + h + 2 < 32) {
                const uint4* np = wpack + (size_t)(kt + h + 2) * 256;
#pragma unroll
                for (int q = 0; q < 4; ++q) P[h][q] = np[q * 64 + lane];
            }
#pragma unroll
            for (int rt = 0; rt < 2; ++rt) {
                f32x4 acc = {0.f, 0.f, 0.f, 0.f};
                acc = __builtin_amdgcn_mfma_f32_16x16x32_bf16(afr[rt][0][0], bh0, acc, 0, 0, 0);
                acc = __builtin_amdgcn_mfma_f32_16x16x32_bf16(afr[rt][0][0], bl0, acc, 0, 0, 0);
                acc = __builtin_amdgcn_mfma_f32_16x16x32_bf16(afr[rt][0][1], bh0, acc, 0, 0, 0);
                acc = __builtin_amdgcn_mfma_f32_16x16x32_bf16(afr[rt][1][0], bh1, acc, 0, 0, 0);
                acc = __builtin_amdgcn_mfma_f32_16x16x32_bf16(afr[rt][1][0], bl1, acc, 0, 0, 0);
                acc = __builtin_amdgcn_mfma_f32_16x16x32_bf16(afr[rt][1][1], bh1, acc, 0, 0, 0);
#pragma unroll
                for (int r = 0; r < 4; ++r) {
                    float s = fmaf(-2.f, acc[r], wsqv);
                    // min2' = median(min1, min2, s): valid since min1 <= min2.
                    min2[rt][r] = __builtin_amdgcn_fmed3f(min1[rt][r], min2[rt][r], s);
                    bool lt = s < min1[rt][r];
                    idx[rt][r]  = lt ? kg : idx[rt][r];
                    min1[rt][r] = fminf(min1[rt][r], s);
                }
            }
        }
    }

    // Reduce across the 16 k-columns (low 4 lane bits).
#pragma unroll
    for (int d = 1; d < 16; d <<= 1) {
#pragma unroll
        for (int rt = 0; rt < 2; ++rt)
#pragma unroll
            for (int r = 0; r < 4; ++r) {
                float o1 = __shfl_xor(min1[rt][r], d);
                float o2 = __shfl_xor(min2[rt][r], d);
                int   oi = __shfl_xor(idx[rt][r], d);
                if (o1 < min1[rt][r]) {
                    min2[rt][r] = fminf(min1[rt][r], o2);
                    min1[rt][r] = o1; idx[rt][r] = oi;
                } else {
                    min2[rt][r] = fminf(min2[rt][r], o1);
                }
            }
    }
    if (m == 0) {
#pragma unroll
        for (int rt = 0; rt < 2; ++rt)
#pragma unroll
            for (int r = 0; r < 4; ++r) {
                const int rowg = wvid * 32 + rt * 16 + quad * 4 + r;
                const bool fl = (min2[rt][r] - min1[rt][r]) < THRESH;
                sidx[rowg] = fl ? -1 : idx[rt][r];
                if (!fl) atomicAdd(&hcnt[idx[rt][r]], 1u);
            }
    }
    __syncthreads();   // sidx ready

    // Epilogue: thread (rb=tid&127, cg=tid>>7) handles 32 channels of row rb.
    // Flagged rows: write out_idx=-1 (marker for vq_fix), skip q/loss.
    {
        const int rb = tid & 127, cg = tid >> 7;
        const int bk = sidx[rb];
        float dsum = 0.f;
        if (cg == 0) out_idx[n0 + rb] = (float)bk;   // -1 marker when flagged
        if (bk >= 0) {
            const float4* wb = (const float4*)(w + (size_t)bk * DIM + cg * 32);
            const float* xq = xbase + rb;
            float* oq = out_q + (size_t)b * 262144 + hw0 + rb;
#pragma unroll
            for (int j4 = 0; j4 < 8; ++j4) {
                float4 v = wb[j4];
                const size_t c = (size_t)(cg * 32 + j4 * 4) * 4096;
                float e0 = v.x - xq[c];
                float e1 = v.y - xq[c + 4096];
                float e2 = v.z - xq[c + 8192];
                float e3 = v.w - xq[c + 12288];
                dsum = fmaf(e0, e0, dsum);
                dsum = fmaf(e1, e1, dsum);
                dsum = fmaf(e2, e2, dsum);
                dsum = fmaf(e3, e3, dsum);
                oq[c] = v.x;
                oq[c + 4096] = v.y;
                oq[c + 8192] = v.z;
                oq[c + 12288] = v.w;
            }
        }
#pragma unroll
        for (int off = 32; off > 0; off >>= 1) dsum += __shfl_down(dsum, off);
        if (lane == 0) wred[wvid] = dsum;
    }
    __syncthreads();
    if (tid == 0)
        atomicAdd(loss_sum, (wred[0] + wred[1]) + (wred[2] + wred[3]));
    for (int i = tid; i < NUM_K; i += 256) {
        unsigned cc = hcnt[i];
        if (cc) atomicAdd(&counts[i], cc);
    }
}

// Phase 2: scan out_idx for -1 markers; for each flagged row run the frozen
// bitwise argmin (coalesced via fp32 transposed wt[c][k]) + full epilogue.
// One wave per 64-row slab; all lanes share the ballot mask (uniform loop).
__global__ __launch_bounds__(64) void vq_fix(
        const float* __restrict__ x, const float* __restrict__ w,
        const float* __restrict__ wt, const float* __restrict__ swsq_g,
        float* __restrict__ out_idx, float* __restrict__ out_q,
        float* __restrict__ loss_sum, unsigned* __restrict__ counts) {
    __shared__ float xrow[DIM];
    const int lane = threadIdx.x;
    const int n0 = blockIdx.x * 64;
    unsigned long long mask = __ballot(out_idx[n0 + lane] < 0.f);
    while (mask) {
        const int j = __ffsll((long long)mask) - 1;
        mask &= mask - 1;
        const int n = n0 + j;
        const int b = n >> 12, hw = n & 4095;
        const size_t xoff = (size_t)b * 262144 + (size_t)lane * 4096 + hw;
        const float xv = x[xoff];
        xrow[lane] = xv;
        __syncthreads();
        // frozen xsq
        float p0 = 0.f, p1 = 0.f, p2 = 0.f, p3 = 0.f;
#pragma unroll
        for (int c = 0; c < DIM; c += 4) {
            p0 = fmaf(xrow[c + 0], xrow[c + 0], p0);
            p1 = fmaf(xrow[c + 1], xrow[c + 1], p1);
            p2 = fmaf(xrow[c + 2], xrow[c + 2], p2);
            p3 = fmaf(xrow[c + 3], xrow[c + 3], p3);
        }
        const float xsq = __fadd_rn(__fadd_rn(p0, p1), __fadd_rn(p2, p3));
        float best = 3.4e38f; int bk = 1 << 30;
#pragma unroll 1
        for (int t = 0; t < 8; ++t) {
            const int k = 64 * t + lane;
            float d = 0.f;
#pragma unroll
            for (int c = 0; c < DIM; ++c)
                d = fmaf(xrow[c], wt[c * NUM_K + k], d);   // coalesced 256 B
            const float s = __fsub_rn(__fadd_rn(xsq, swsq_g[k]),
                                      __fmul_rn(2.f, d));
            if (s < best || (s == best && k < bk)) { best = s; bk = k; }
        }
#pragma unroll
        for (int d = 1; d < 64; d <<= 1) {
            float ob = __shfl_xor(best, d);
            int   oi = __shfl_xor(bk, d);
            if (ob < best || (ob == best && oi < bk)) { best = ob; bk = oi; }
        }
        // Epilogue in the same wave.
        const float wv = w[(size_t)bk * DIM + lane];
        out_q[xoff] = wv;
        float e = wv - xv;
        float e2 = e * e;
#pragma unroll
        for (int d = 32; d > 0; d >>= 1) e2 += __shfl_down(e2, d);
        if (lane == 0) {
            out_idx[n] = (float)bk;
            atomicAdd(loss_sum, e2);
            atomicAdd(&counts[bk], 1u);
        }
        __syncthreads();
    }
}

__global__ __launch_bounds__(512) void vq_final(
        const unsigned* __restrict__ counts,
        const float* __restrict__ loss_sum,
        float* __restrict__ out) {
    __shared__ float red[8];
    const int tid = threadIdx.x;
    float p = (float)counts[tid] * (1.f / (float)NROWS);  // /131072 exact
    float t = p * logf(p + 1e-10f);
#pragma unroll
    for (int off = 32; off > 0; off >>= 1) t += __shfl_down(t, off);
    if ((tid & 63) == 0) red[tid >> 6] = t;
    __syncthreads();
    if (tid == 0) {
        float s = 0.f;
#pragma unroll
        for (int i = 0; i < 8; ++i) s += red[i];
        out[PERP_OFF] = expf(-s);
        // loss = q_latent + 0.25*e_latent = 1.25 * MSE (forward values equal)
        out[0] = loss_sum[0] * (1.25f / (float)NELEM);
    }
}

extern "C" void kernel_launch(void* const* d_in, const int* in_sizes, int n_in,
                              void* d_out, int out_size, void* d_ws, size_t ws_size,
                              hipStream_t stream) {
    const float* x = (const float*)d_in[0];
    const float* w = (const float*)d_in[1];
    float* out = (float*)d_out;
    char* ws = (char*)d_ws;
    float*    loss_sum = (float*)ws;
    unsigned* counts   = (unsigned*)(ws + 16);
    float*    swsq_g   = (float*)(ws + 4096);
    unsigned short* wpack = (unsigned short*)(ws + 8192);
    float*    wt       = (float*)(ws + 139264);

    // ws re-poisoned to 0xAA each launch: zero loss/counts.
    hipMemsetAsync(d_ws, 0, 2064, stream);

    vq_prep<<<128, 256, 0, stream>>>(w, swsq_g, wpack, wt);
    vq_phase1<<<NROWS / 128, 256, 0, stream>>>(x, w, swsq_g, (const uint4*)wpack,
                                               out + Q_OFF, out + IDX_OFF,
                                               loss_sum, counts);
    vq_fix<<<NROWS / 64, 64, 0, stream>>>(x, w, wt, swsq_g,
                                          out + IDX_OFF, out + Q_OFF,
                                          loss_sum, counts);
    vq_final<<<1, 512, 0, stream>>>(counts, loss_sum, out);
}

// Round 10
// 163.252 us; speedup vs baseline: 3.6728x; 3.6728x over previous
//
#include <hip/hip_runtime.h>
#include <math.h>

// Problem constants (fixed by the reference).
#define NUM_K   512        // codebook entries
#define DIM     64         // embedding dim (== C)
#define NROWS   131072     // 32*64*64 flattened (b,h,w) rows
#define NELEM   8388608    // NROWS*DIM
// d_out layout (float32, concatenated in return order):
// [0] loss ; [1..1+NELEM) quantized NCHW ; [1+NELEM] perplexity ;
// [2+NELEM..) codebook_indices (as float)
#define Q_OFF    1
#define PERP_OFF 8388609
#define IDX_OFF  8388610

// Candidate margin: approx-score error eps<=1.2e-5 (bf16 hi/lo MFMA, incl.
// dropped xl*wl), ref fp32 grid noise eta<=1.52e-5 -> need M > 2eps+2eta
// = 5.5e-5. M=1e-4 gives ~2x safety. Rows' ks with s' > s'min+M provably
// cannot be the reference argmin; candidates get frozen bitwise evaluation.
#define MARGIN  1.0e-4f

typedef short  bf16x8 __attribute__((ext_vector_type(8)));
typedef float  f32x4  __attribute__((ext_vector_type(4)));

// ws layout:
//   [0,4)         float loss_sum
//   [16,2064)     uint  counts[512]
//   [4096,6144)   float swsq_g[512]        (frozen bitwise ||w_k||^2)
//   [8192,139264) ushort wpack[65536]      (B-fragment-packed hi/lo codebook)

__device__ __forceinline__ unsigned short f2bf(float f) {  // RNE f32->bf16
    unsigned u = __float_as_uint(f);
    return (unsigned short)((u + 0x7FFFu + ((u >> 16) & 1u)) >> 16);
}
__device__ __forceinline__ float bf2f(unsigned short h) {
    return __uint_as_float(((unsigned)h) << 16);
}

// Frozen bitwise reference score (verified round 2): sequential fmaf chain
// c=0..63, s = fl(fl(xsq+wsq)-fl(2*dot)). Packed (bits(s)<<32)|k: s>0 always
// (~64), so u64 min = lexicographic (s,k) = np.argmin first-occurrence rule.
__device__ __forceinline__ unsigned long long eval_chain(
        const float* __restrict__ xr, float xsq,
        const float* __restrict__ w, float wsq, int k) {
    const float* wk = w + (size_t)k * DIM;
    float d = 0.f;
#pragma unroll
    for (int c = 0; c < DIM; c += 4) {
        float4 wv = *(const float4*)(wk + c);
        d = fmaf(xr[c + 0], wv.x, d);
        d = fmaf(xr[c + 1], wv.y, d);
        d = fmaf(xr[c + 2], wv.z, d);
        d = fmaf(xr[c + 3], wv.w, d);
    }
    float s = __fsub_rn(__fadd_rn(xsq, wsq), __fmul_rn(2.f, d));
    return ((unsigned long long)__float_as_uint(s) << 32) | (unsigned)k;
}

// Prep (validated): frozen wsq (numpy pairwise leaf) + B-fragment hi/lo
// packing for mfma_f32_16x16x32_bf16: B[k=(lane>>4)*8+j][n=lane&15].
__global__ __launch_bounds__(256) void vq_prep(const float* __restrict__ w,
                                               float* __restrict__ swsq_g,
                                               unsigned short* __restrict__ wpack) {
    const int id = blockIdx.x * 256 + threadIdx.x;   // 0..8191
    if (id < NUM_K) {
        const float* wk = w + id * DIM;
        float r[8];
#pragma unroll
        for (int j = 0; j < 8; ++j) r[j] = __fmul_rn(wk[j], wk[j]);
#pragma unroll
        for (int t = 1; t < 8; ++t)
#pragma unroll
            for (int j = 0; j < 8; ++j)
                r[j] = __fadd_rn(r[j], __fmul_rn(wk[8 * t + j], wk[8 * t + j]));
        swsq_g[id] = __fadd_rn(
            __fadd_rn(__fadd_rn(r[0], r[1]), __fadd_rn(r[2], r[3])),
            __fadd_rn(__fadd_rn(r[4], r[5]), __fadd_rn(r[6], r[7])));
    }
    const int kt = id >> 8, f = (id >> 6) & 3, l = id & 63;
    const int step = f >> 1, pass = f & 1;
    const int coln = kt * 16 + (l & 15), quad = l >> 4;
    const float* src = w + (size_t)coln * DIM + step * 32 + quad * 8;
    unsigned short tmp[8];
#pragma unroll
    for (int j = 0; j < 8; ++j) {
        float v = src[j];
        unsigned short hi = f2bf(v);
        tmp[j] = pass ? f2bf(v - bf2f(hi)) : hi;
    }
    *(uint4*)(wpack + (size_t)id * 8) = *(uint4*)tmp;
}

// Single main kernel: MFMA approx pass (top-3 per lane tracked) -> in-block
// frozen exact evaluation of candidate ks -> rare full rescans -> epilogue.
__global__ __launch_bounds__(256, 3) void vq_phase1(
        const float* __restrict__ x,
        const float* __restrict__ w,
        const float* __restrict__ swsq_g,
        const uint4* __restrict__ wpack,
        float* __restrict__ out_q,
        float* __restrict__ out_idx,
        float* __restrict__ loss_sum,
        unsigned* __restrict__ counts) {
    __shared__ float swsq[NUM_K];              // 2 KB
    __shared__ unsigned hcnt[NUM_K];           // 2 KB
    __shared__ float xs[128 * 65];             // x rows, stride 65: 33.3 KB
    __shared__ float sxsq[128];                // frozen xsq per row
    __shared__ int sidx[128];                  // final index per row
    __shared__ float wred[4];
    __shared__ unsigned long long rred[4];
    __shared__ int rlist[128];
    __shared__ int rcount;

    const int tid  = threadIdx.x;
    const int lane = tid & 63;
    const int wvid = tid >> 6;
    const int quad = lane >> 4;
    const int m    = lane & 15;
    const int n0   = blockIdx.x * 128;
    const int b    = n0 >> 12;
    const int hw0  = n0 & 4095;
    const float* xbase = x + (size_t)b * 262144 + hw0;

    if (tid == 0) rcount = 0;
    for (int i = tid; i < NUM_K; i += 256) { swsq[i] = swsq_g[i]; hcnt[i] = 0; }

    // Stage x -> xs (stride-65: conflict-free) + A fragments in registers.
    bf16x8 afr[2][2][2];
#pragma unroll
    for (int rt = 0; rt < 2; ++rt) {
        const int row = wvid * 32 + rt * 16 + m;
        const float* xp = xbase + row;
#pragma unroll
        for (int s = 0; s < 2; ++s) {
            union { bf16x8 v; unsigned short u[8]; } hi, lo;
#pragma unroll
            for (int j = 0; j < 8; ++j) {
                const int c = s * 32 + quad * 8 + j;
                float v = xp[(size_t)c * 4096];
                xs[row * 65 + c] = v;
                unsigned short h = f2bf(v);
                hi.u[j] = h;
                lo.u[j] = f2bf(v - bf2f(h));
            }
            afr[rt][s][0] = hi.v;
            afr[rt][s][1] = lo.v;
        }
    }
    __syncthreads();   // xs ready

    // Frozen xsq per row (bitwise same form as verified rounds 2-9).
    if (tid < 128) {
        const float* xr = &xs[tid * 65];
        float p0 = 0.f, p1 = 0.f, p2 = 0.f, p3 = 0.f;
#pragma unroll
        for (int c = 0; c < DIM; c += 4) {
            p0 = fmaf(xr[c + 0], xr[c + 0], p0);
            p1 = fmaf(xr[c + 1], xr[c + 1], p1);
            p2 = fmaf(xr[c + 2], xr[c + 2], p2);
            p3 = fmaf(xr[c + 3], xr[c + 3], p3);
        }
        sxsq[tid] = __fadd_rn(__fadd_rn(p0, p1), __fadd_rn(p2, p3));
    }
    __syncthreads();   // sxsq/swsq/rcount ready

    // Approx k-loop: track top-3 values + top-2 indices per lane-class.
    float min1[2][4], min2[2][4], min3[2][4]; int idx1[2][4], idx2[2][4];
#pragma unroll
    for (int rt = 0; rt < 2; ++rt)
#pragma unroll
        for (int r = 0; r < 4; ++r) {
            min1[rt][r] = 3.4e38f; min2[rt][r] = 3.4e38f; min3[rt][r] = 3.4e38f;
            idx1[rt][r] = 0; idx2[rt][r] = 0;
        }

    uint4 P[2][4];
    {
        const uint4* t0 = wpack;
        const uint4* t1 = wpack + 256;
#pragma unroll
        for (int q = 0; q < 4; ++q) { P[0][q] = t0[q * 64 + lane];
                                      P[1][q] = t1[q * 64 + lane]; }
    }
#pragma unroll 1
    for (int kt = 0; kt < 32; kt += 2) {
#pragma unroll
        for (int h = 0; h < 2; ++h) {
            bf16x8 bh0 = __builtin_bit_cast(bf16x8, P[h][0]);
            bf16x8 bl0 = __builtin_bit_cast(bf16x8, P[h][1]);
            bf16x8 bh1 = __builtin_bit_cast(bf16x8, P[h][2]);
            bf16x8 bl1 = __builtin_bit_cast(bf16x8, P[h][3]);
            const int kg = (kt + h) * 16 + m;
            const float wsqv = swsq[kg];
            if (kt + h + 2 < 32) {
                const uint4* np = wpack + (size_t)(kt + h + 2) * 256;
#pragma unroll
                for (int q = 0; q < 4; ++q) P[h][q] = np[q * 64 + lane];
            }
#pragma unroll
            for (int rt = 0; rt < 2; ++rt) {
                f32x4 acc = {0.f, 0.f, 0.f, 0.f};
                acc = __builtin_amdgcn_mfma_f32_16x16x32_bf16(afr[rt][0][0], bh0, acc, 0, 0, 0);
                acc = __builtin_amdgcn_mfma_f32_16x16x32_bf16(afr[rt][0][0], bl0, acc, 0, 0, 0);
                acc = __builtin_amdgcn_mfma_f32_16x16x32_bf16(afr[rt][0][1], bh0, acc, 0, 0, 0);
                acc = __builtin_amdgcn_mfma_f32_16x16x32_bf16(afr[rt][1][0], bh1, acc, 0, 0, 0);
                acc = __builtin_amdgcn_mfma_f32_16x16x32_bf16(afr[rt][1][0], bl1, acc, 0, 0, 0);
                acc = __builtin_amdgcn_mfma_f32_16x16x32_bf16(afr[rt][1][1], bh1, acc, 0, 0, 0);
#pragma unroll
                for (int r = 0; r < 4; ++r) {
                    float s = fmaf(-2.f, acc[r], wsqv);
                    bool lt1 = s < min1[rt][r];
                    bool lt2 = s < min2[rt][r];
                    min3[rt][r] = __builtin_amdgcn_fmed3f(min2[rt][r], min3[rt][r], s);
                    idx2[rt][r] = lt1 ? idx1[rt][r] : (lt2 ? kg : idx2[rt][r]);
                    min2[rt][r] = __builtin_amdgcn_fmed3f(min1[rt][r], min2[rt][r], s);
                    idx1[rt][r] = lt1 ? kg : idx1[rt][r];
                    min1[rt][r] = fminf(min1[rt][r], s);
                }
            }
        }
    }

    // Per-rowslot resolution: gmin reduce, candidate exact chains, u64 reduce.
#pragma unroll 1
    for (int rt = 0; rt < 2; ++rt)
#pragma unroll 1
        for (int r = 0; r < 4; ++r) {
            float g1 = min1[rt][r]; int gi = idx1[rt][r];
#pragma unroll
            for (int d = 1; d < 16; d <<= 1) {
                float og = __shfl_xor(g1, d);
                int   oi = __shfl_xor(gi, d);
                if (og < g1) { g1 = og; gi = oi; }
            }
            const float lim = g1 + MARGIN;
            const bool c1 = min1[rt][r] <= lim;
            const bool c2 = min2[rt][r] <= lim;
            const bool f3 = min3[rt][r] <= lim;
            unsigned long long b1 = __ballot(c1);
            unsigned long long b2 = __ballot(c2);
            unsigned long long b3 = __ballot(f3);
            const unsigned fld1 = (unsigned)(b1 >> (quad * 16)) & 0xFFFFu;
            const unsigned fld2 = (unsigned)(b2 >> (quad * 16)) & 0xFFFFu;
            const unsigned fld3 = (unsigned)(b3 >> (quad * 16)) & 0xFFFFu;
            const int  nc   = __popc(fld1) + __popc(fld2);
            const bool flag = fld3 != 0;   // >=3 same-class within M: rescan
            const int rowL = wvid * 32 + rt * 16 + quad * 4 + r;
            unsigned long long best = ~0ull;
            if (!flag && nc > 1) {
                const float* xr = &xs[rowL * 65];
                const float xq = sxsq[rowL];
                const int k1 = c1 ? idx1[rt][r] : idx2[rt][r];
                if (c1 || c2) best = eval_chain(xr, xq, w, swsq[k1], k1);
                if (c1 && c2) {
                    unsigned long long e =
                        eval_chain(xr, xq, w, swsq[idx2[rt][r]], idx2[rt][r]);
                    best = e < best ? e : best;
                }
            }
#pragma unroll
            for (int d = 1; d < 16; d <<= 1) {
                unsigned long long o = __shfl_xor(best, d);
                best = o < best ? o : best;
            }
            if (m == 0) {
                if (flag) rlist[atomicAdd(&rcount, 1)] = rowL;
                else sidx[rowL] = (nc > 1) ? (int)(best & 0xFFFFFFFFull) : gi;
            }
        }
    __syncthreads();   // sidx (candidate path) + rlist/rcount ready

    // Full exact rescan for flagged rows (rare, ~0.3%): whole block, 2 k/thr.
    const int rc = rcount;
#pragma unroll 1
    for (int i = 0; i < rc; ++i) {
        const int rowL = rlist[i];
        const float* xr = &xs[rowL * 65];
        const float xq = sxsq[rowL];
        unsigned long long bb = eval_chain(xr, xq, w, swsq[tid], tid);
        unsigned long long e2 = eval_chain(xr, xq, w, swsq[tid + 256], tid + 256);
        if (e2 < bb) bb = e2;
#pragma unroll
        for (int d = 1; d < 64; d <<= 1) {
            unsigned long long o = __shfl_xor(bb, d);
            if (o < bb) bb = o;
        }
        if (lane == 0) rred[wvid] = bb;
        __syncthreads();
        if (tid == 0) {
            unsigned long long q0 = rred[0] < rred[1] ? rred[0] : rred[1];
            unsigned long long q1 = rred[2] < rred[3] ? rred[2] : rred[3];
            sidx[rowL] = (int)((q0 < q1 ? q0 : q1) & 0xFFFFFFFFull);
        }
        __syncthreads();
    }

    // Epilogue: thread (rb=tid&127, cg=tid>>7) handles 32 channels of row rb;
    // x from LDS (no global re-read).
    {
        const int rb = tid & 127, cg = tid >> 7;
        const int bk = sidx[rb];
        const float* xr = &xs[rb * 65];
        float dsum = 0.f;
        const float4* wb = (const float4*)(w + (size_t)bk * DIM + cg * 32);
        float* oq = out_q + (size_t)b * 262144 + hw0 + rb;
        if (cg == 0) {
            out_idx[n0 + rb] = (float)bk;
            atomicAdd(&hcnt[bk], 1u);
        }
#pragma unroll
        for (int j4 = 0; j4 < 8; ++j4) {
            float4 v = wb[j4];
            const int c = cg * 32 + j4 * 4;
            float e0 = v.x - xr[c + 0];
            float e1 = v.y - xr[c + 1];
            float e2 = v.z - xr[c + 2];
            float e3 = v.w - xr[c + 3];
            dsum = fmaf(e0, e0, dsum);
            dsum = fmaf(e1, e1, dsum);
            dsum = fmaf(e2, e2, dsum);
            dsum = fmaf(e3, e3, dsum);
            oq[(size_t)(c + 0) * 4096] = v.x;
            oq[(size_t)(c + 1) * 4096] = v.y;
            oq[(size_t)(c + 2) * 4096] = v.z;
            oq[(size_t)(c + 3) * 4096] = v.w;
        }
#pragma unroll
        for (int off = 32; off > 0; off >>= 1) dsum += __shfl_down(dsum, off);
        if (lane == 0) wred[wvid] = dsum;
    }
    __syncthreads();
    if (tid == 0)
        atomicAdd(loss_sum, (wred[0] + wred[1]) + (wred[2] + wred[3]));
    for (int i = tid; i < NUM_K; i += 256) {
        unsigned cc = hcnt[i];
        if (cc) atomicAdd(&counts[i], cc);
    }
}

__global__ __launch_bounds__(512) void vq_final(
        const unsigned* __restrict__ counts,
        const float* __restrict__ loss_sum,
        float* __restrict__ out) {
    __shared__ float red[8];
    const int tid = threadIdx.x;
    float p = (float)counts[tid] * (1.f / (float)NROWS);  // /131072 exact
    float t = p * logf(p + 1e-10f);
#pragma unroll
    for (int off = 32; off > 0; off >>= 1) t += __shfl_down(t, off);
    if ((tid & 63) == 0) red[tid >> 6] = t;
    __syncthreads();
    if (tid == 0) {
        float s = 0.f;
#pragma unroll
        for (int i = 0; i < 8; ++i) s += red[i];
        out[PERP_OFF] = expf(-s);
        // loss = q_latent + 0.25*e_latent = 1.25 * MSE (forward values equal)
        out[0] = loss_sum[0] * (1.25f / (float)NELEM);
    }
}

extern "C" void kernel_launch(void* const* d_in, const int* in_sizes, int n_in,
                              void* d_out, int out_size, void* d_ws, size_t ws_size,
                              hipStream_t stream) {
    const float* x = (const float*)d_in[0];
    const float* w = (const float*)d_in[1];
    float* out = (float*)d_out;
    char* ws = (char*)d_ws;
    float*    loss_sum = (float*)ws;
    unsigned* counts   = (unsigned*)(ws + 16);
    float*    swsq_g   = (float*)(ws + 4096);
    unsigned short* wpack = (unsigned short*)(ws + 8192);

    // ws re-poisoned to 0xAA each launch: zero loss/counts.
    hipMemsetAsync(d_ws, 0, 2064, stream);

    vq_prep<<<32, 256, 0, stream>>>(w, swsq_g, wpack);
    vq_phase1<<<NROWS / 128, 256, 0, stream>>>(x, w, swsq_g, (const uint4*)wpack,
                                               out + Q_OFF, out + IDX_OFF,
                                               loss_sum, counts);
    vq_final<<<1, 512, 0, stream>>>(counts, loss_sum, out);
}